// Round 2
// baseline (82.426 us; speedup 1.0000x reference)
//
#include <hip/hip_runtime.h>

// ===========================================================================
// Reformulation: the circuit (RY/CNOT only) is a fixed REAL LINEAR operator.
//   out = softmax_j( || P_j U x ||^2 / ||x||^2 ),  U in R^{128x128} orthogonal,
//   P_j selects states s with s&3 == j (wires 5,6 -> state bits 1,0).
// Kernel A: simulate the verified gate sequence on the 128 basis vectors to
//           build Ut[k][s] = U[s][k] in d_ws (64 KiB). 1 basis state per wave
//           (64 lanes x 2 regs), ~3x shorter serial chain than the old v8
//           layout, and only 1/32 of the old total gate work.
// Kernel B: fused 4096x128 @ 128x128 fp32 matmul + squared-sum + softmax.
//           U cached in LDS; x broadcast via __shfl; 1024 independent FMAs
//           per thread -> throughput-bound, no serial gate chain.
//
// Dtype evidence log (carried over): inputs fp32, OUTPUT fp32 (float*).
// R0/R1: GPUAcquisitionTimeout (infra) — no data. Resubmitting unchanged
// after a correctness self-review (wire->bit maps, transpose convention,
// group-local shuffles, s&3 grouping all re-verified by hand).
// ===========================================================================

#define DEVI __device__ __forceinline__

// ---------------- Kernel A primitives: s = (lane<<1)|r -----------------------
// wire w in [0,5] -> lane bit (5-w)  (mask 32>>w); wire 6 -> reg bit r.

DEVI void a_ry_lane(float v[2], int lmask, float c, float s, int lane) {
    float ss = (lane & lmask) ? s : -s;   // bit=1: c*me + s*partner ; bit=0: c*me - s*partner
    float p0 = __shfl_xor(v[0], lmask, 64);
    float p1 = __shfl_xor(v[1], lmask, 64);
    v[0] = fmaf(c, v[0], ss * p0);
    v[1] = fmaf(c, v[1], ss * p1);
}

DEVI void a_ry_reg(float v[2], float c, float s) {
    float a = v[0], b = v[1];
    v[0] = fmaf(c, a, -(s * b));   // a' = c*a - s*b
    v[1] = fmaf(c, b,  (s * a));   // b' = s*a + c*b
}

DEVI void a_ry(float v[2], int w, float c, float s, int lane) {
    if (w < 6) a_ry_lane(v, 32 >> w, c, s, lane);
    else       a_ry_reg(v, c, s);
}

DEVI void a_cnot(float v[2], int cw, int tw, int lane) {
    if (cw < 6 && tw < 6) {                 // lane-lane
        int cm = 32 >> cw, tm = 32 >> tw;
        bool hit = (lane & cm) != 0;
        float p0 = __shfl_xor(v[0], tm, 64);
        float p1 = __shfl_xor(v[1], tm, 64);
        v[0] = hit ? p0 : v[0];
        v[1] = hit ? p1 : v[1];
    } else if (cw < 6) {                    // target = wire 6 (reg bit)
        int cm = 32 >> cw;
        bool hit = (lane & cm) != 0;
        float a = v[0], b = v[1];
        v[0] = hit ? b : a;
        v[1] = hit ? a : b;
    } else {                                // control = wire 6 (reg bit), lane target
        int tm = 32 >> tw;
        v[1] = __shfl_xor(v[1], tm, 64);    // control=1 subspace is exactly r==1
    }
}

// ---------------- Kernel A: build Ut[k][s] = U[s][k] -------------------------
__global__ __launch_bounds__(64) void build_u_kernel(
    const float* __restrict__ QC1, const float* __restrict__ QC2,
    const float* __restrict__ QC3, const float* __restrict__ QP1,
    const float* __restrict__ QP2, const float* __restrict__ QP3,
    const float* __restrict__ QF,
    float* __restrict__ U)
{
    const int lane = threadIdx.x & 63;
    const int k    = blockIdx.x;           // basis index 0..127 (input column)

    float v[2];
    v[0] = ((lane << 1)     == k) ? 1.0f : 0.0f;
    v[1] = ((lane << 1) + 1 == k) ? 1.0f : 0.0f;

    float cc[12], sv[12];

    // ---- conv block 1 ----
#pragma unroll
    for (int t = 0; t < 12; ++t) __sincosf(0.5f * QC1[t], &sv[t], &cc[t]);
#pragma unroll
    for (int i = 0; i < 7; ++i) {
        const int i2 = (i + 1) % 7;
#pragma unroll
        for (int q = 0; q < 6; ++q) {
            a_ry(v, i,  cc[2*q],   sv[2*q],   lane);
            a_ry(v, i2, cc[2*q+1], sv[2*q+1], lane);
            a_cnot(v, i, i2, lane);
        }
    }

    // ---- pool 1 ----
    {
        float c0, s0, c1, s1;
        __sincosf(0.5f * QP1[0], &s0, &c0);
        __sincosf(0.5f * QP1[1], &s1, &c1);
#pragma unroll
        for (int i = 0; i < 3; ++i) {
            a_ry(v, i,     c0,  s0, lane);
            a_ry(v, i + 3, c1,  s1, lane);
            a_cnot(v, i, i + 3, lane);
            a_ry(v, i + 3, c1, -s1, lane);
        }
    }

    // ---- conv block 2 (i==6: RY partner wire 3, CNOT target wire 0) ----
#pragma unroll
    for (int t = 0; t < 12; ++t) __sincosf(0.5f * QC2[t], &sv[t], &cc[t]);
#pragma unroll
    for (int i = 3; i < 7; ++i) {
        const int ti = (i != 6) ? (i + 1) : 3;
        const int ct = (i != 6) ? (i + 1) : 0;
#pragma unroll
        for (int q = 0; q < 6; ++q) {
            a_ry(v, i,  cc[2*q],   sv[2*q],   lane);
            a_ry(v, ti, cc[2*q+1], sv[2*q+1], lane);
            a_cnot(v, i, ct, lane);
        }
    }

    // ---- pool 2 ----
    {
        float c0, s0, c1, s1;
        __sincosf(0.5f * QP2[0], &s0, &c0);
        __sincosf(0.5f * QP2[1], &s1, &c1);
#pragma unroll
        for (int i = 3; i < 5; ++i) {
            a_ry(v, i,     c0,  s0, lane);
            a_ry(v, i + 2, c1,  s1, lane);
            a_cnot(v, i, i + 2, lane);
            a_ry(v, i + 2, c1, -s1, lane);
        }
    }

    // ---- conv block 3 (leaked loop var -> CNOT(4,5)) ----
#pragma unroll
    for (int t = 0; t < 12; ++t) __sincosf(0.5f * QC3[t], &sv[t], &cc[t]);
#pragma unroll
    for (int q = 0; q < 6; ++q) {
        a_ry(v, 5, cc[2*q],   sv[2*q],   lane);
        a_ry(v, 6, cc[2*q+1], sv[2*q+1], lane);
        a_cnot(v, 4, 5, lane);
    }

    // ---- pool 3 (leaked loop var -> CNOT(4,6)) ----
    {
        float c0, s0, c1, s1;
        __sincosf(0.5f * QP3[0], &s0, &c0);
        __sincosf(0.5f * QP3[1], &s1, &c1);
        a_ry(v, 5, c0,  s0, lane);
        a_ry(v, 6, c1,  s1, lane);
        a_cnot(v, 4, 6, lane);
        a_ry(v, 6, c1, -s1, lane);
    }

    // ---- final block: four RYs on wire 5 == RY(sum) ----
    {
        float cf, sf;
        __sincosf(0.5f * (QF[0] + QF[1] + QF[2] + QF[3]), &sf, &cf);
        a_ry(v, 5, cf, sf, lane);
    }
    a_cnot(v, 5, 6, lane);
    a_cnot(v, 6, 5, lane);
    // CNOT(7,5), CNOT(8,6): controls fixed in |0> -> identity, omitted.

    // write column k: Ut[k][s], s = lane*2 + r  (coalesced float2)
    *reinterpret_cast<float2*>(U + (size_t)k * 128 + (lane << 1)) =
        make_float2(v[0], v[1]);
}

// ---------------- Kernel B: y = U x, probs, softmax --------------------------
// Block = 256 threads = 16 elems x 16 sub-lanes L. Thread (e, L) accumulates
// y[s] for s in {L*4..L*4+3} u {64+L*4..64+L*4+3}  (s&3 == r preserved).
// U in LDS as Ut[k][s]; per k each 16-lane group reads two contiguous 256B
// spans -> 2-way bank aliasing only (free). x broadcast from regs via __shfl.
__global__ __launch_bounds__(256) void apply_u_kernel(
    const float* __restrict__ x, const float* __restrict__ U,
    float* __restrict__ out, int B)
{
    __shared__ float lds_u[128 * 128];     // 64 KiB

    const int tid  = threadIdx.x;
    const int lane = tid & 63;
    const int L    = lane & 15;
    const int b    = blockIdx.x * 16 + (tid >> 4);

    // prefetch x into regs: v[j] = x[b][L*8 + j]  (issue before staging loop)
    float v[8];
    if (b < B) {
        const float* xb = x + (size_t)b * 128 + L * 8;
        float4 lo = *reinterpret_cast<const float4*>(xb);
        float4 hi = *reinterpret_cast<const float4*>(xb + 4);
        v[0]=lo.x; v[1]=lo.y; v[2]=lo.z; v[3]=lo.w;
        v[4]=hi.x; v[5]=hi.y; v[6]=hi.z; v[7]=hi.w;
    } else {
#pragma unroll
        for (int j = 0; j < 8; ++j) v[j] = 0.0f;
    }

    // stage U (64 KiB) into LDS: 16 float4 per thread, coalesced
    {
        const float4* src = reinterpret_cast<const float4*>(U);
        float4*       dst = reinterpret_cast<float4*>(lds_u);
#pragma unroll
        for (int i = 0; i < 16; ++i) dst[tid + 256 * i] = src[tid + 256 * i];
    }
    __syncthreads();

    float acc[8] = {0.f,0.f,0.f,0.f,0.f,0.f,0.f,0.f};
    const int base = lane & 48;            // this elem's group base lane

    #pragma unroll
    for (int m = 0; m < 16; ++m) {
        float xm[8];
#pragma unroll
        for (int j = 0; j < 8; ++j) xm[j] = __shfl(v[j], base + m, 64);
#pragma unroll
        for (int j = 0; j < 8; ++j) {
            const int k = m * 8 + j;
            const float4 uA = *reinterpret_cast<const float4*>(&lds_u[k * 128 + L * 4]);
            const float4 uB = *reinterpret_cast<const float4*>(&lds_u[k * 128 + 64 + L * 4]);
            acc[0] = fmaf(uA.x, xm[j], acc[0]);
            acc[1] = fmaf(uA.y, xm[j], acc[1]);
            acc[2] = fmaf(uA.z, xm[j], acc[2]);
            acc[3] = fmaf(uA.w, xm[j], acc[3]);
            acc[4] = fmaf(uB.x, xm[j], acc[4]);
            acc[5] = fmaf(uB.y, xm[j], acc[5]);
            acc[6] = fmaf(uB.z, xm[j], acc[6]);
            acc[7] = fmaf(uB.w, xm[j], acc[7]);
        }
    }

    if (b >= B) return;                    // B=4096: groups are uniform, never taken

    // probs over wires (5,6) = s&3: both acc[j] and acc[4+j] have s&3 == j
    float gs[4];
#pragma unroll
    for (int j = 0; j < 4; ++j) gs[j] = acc[j]*acc[j] + acc[4+j]*acc[4+j];
#pragma unroll
    for (int mm = 1; mm < 16; mm <<= 1) {
#pragma unroll
        for (int j = 0; j < 4; ++j) gs[j] += __shfl_xor(gs[j], mm, 64);
    }
    // U orthogonal -> sum(gs) == ||x||^2 ; dividing implements normalize=True
    float n  = gs[0] + gs[1] + gs[2] + gs[3];
    float p0 = gs[0] / n, p1 = gs[1] / n, p2 = gs[2] / n, p3 = gs[3] / n;
    float mx = fmaxf(fmaxf(p0, p1), fmaxf(p2, p3));
    float e0 = __expf(p0 - mx), e1 = __expf(p1 - mx);
    float e2 = __expf(p2 - mx), e3 = __expf(p3 - mx);
    float inv = 1.0f / (e0 + e1 + e2 + e3);

    if (L == 0) {
        float4 o = make_float4(e0 * inv, e1 * inv, e2 * inv, e3 * inv);
        *reinterpret_cast<float4*>(out + (size_t)b * 4) = o;   // fp32 OUTPUT
    }
}

extern "C" void kernel_launch(void* const* d_in, const int* in_sizes, int n_in,
                              void* d_out, int out_size, void* d_ws, size_t ws_size,
                              hipStream_t stream) {
    const float* x   = (const float*)d_in[0];
    const float* QC1 = (const float*)d_in[1];
    const float* QC2 = (const float*)d_in[2];
    const float* QC3 = (const float*)d_in[3];
    const float* QP1 = (const float*)d_in[4];
    const float* QP2 = (const float*)d_in[5];
    const float* QP3 = (const float*)d_in[6];
    const float* QF  = (const float*)d_in[7];
    float* out = (float*)d_out;
    float* U   = (float*)d_ws;            // 128*128*4 = 64 KiB

    const int B = in_sizes[0] / 128;      // 4096

    // Kernel A: 128 basis states, one per wave (128 single-wave blocks)
    build_u_kernel<<<128, 64, 0, stream>>>(QC1, QC2, QC3, QP1, QP2, QP3, QF, U);
    // Kernel B: fused matmul + epilogue
    apply_u_kernel<<<(B + 15) / 16, 256, 0, stream>>>(x, U, out, B);
}